// Round 1
// 688.557 us; speedup vs baseline: 1.3550x; 1.3550x over previous
//
#include <hip/hip_runtime.h>
#include <hip/hip_bf16.h>
#include <hip/hip_fp16.h>

// MetaGIN round 5: k_agg rewritten — uniform-index weight broadcast via
// ds_swizzle (kills the divergent register-array select chains), packed-f16
// v_dot2_f32_f16 inner product (kills bf16 unpack ops), pk_add_f16 for
// h0+h1, cvt_pkrtz repack, rcp/rsq fast ops, next-edge prefetch.
// Conv weights (gate/value) now stored as f16 in the arena; everything else
// unchanged from R4.
//
// ws layout: agg N*128 f32 | h1 N*128 f16 | pb16 arena | gemb 33*128 f32 |
//            cnt N i32 | off N i32 | bsum 1024 i32 | ssrc E u32 | sattr E u32
// h0 (N*128 f16) lives in d_out (fully overwritten by k_post at the end).

typedef unsigned short u16;
typedef unsigned int   u32;

#define WIDTH 128

// params_b16 element offsets (bf16 except GW/VW which are f16)
#define OFF_W0   0        // 16384
#define OFF_B0   16384    // 128
#define OFF_W1   16512    // 16384
#define OFF_B1   32896    // 128
#define OFF_EMB  33024    // 33*128 = 4224
#define OFF_GW   37248    // 128*16 = 2048 (f16)
#define OFF_VW   39296    // 2048 (f16)
#define OFF_PW   41344    // 16384
#define OFF_PB   57728    // 128
#define OFF_DP   57856    // 128
#define OFF_DEG  57984    // N
#define ARENA_PAD 258048  // u16 elems (>= OFF_DEG+N, even)

typedef __attribute__((ext_vector_type(8))) short bf16x8;
typedef __attribute__((ext_vector_type(4))) float f32x4;
typedef __attribute__((ext_vector_type(2))) __fp16 f16x2;

__device__ __forceinline__ float bfl(u32 p){ return __uint_as_float(p << 16); }
__device__ __forceinline__ float bfh(u32 p){ return __uint_as_float(p & 0xffff0000u); }
__device__ __forceinline__ float b2f(u16 u){ return __uint_as_float(((u32)u) << 16); }
__device__ __forceinline__ u16   f2b(float f){
  u32 u = __float_as_uint(f);
  u += 0x7fffu + ((u >> 16) & 1u);   // RNE
  return (u16)(u >> 16);
}
__device__ __forceinline__ u16   f2h(float f){ return __half_as_ushort(__float2half(f)); }

__device__ __forceinline__ f16x2 u2h(u32 u){ union { u32 a; f16x2 b; } c; c.a = u; return c.b; }
__device__ __forceinline__ u32   h2u(f16x2 h){ union { f16x2 b; u32 a; } c; c.b = h; return c.a; }

__device__ __forceinline__ float dot2h(f16x2 a, f16x2 b, float c){
#if __has_builtin(__builtin_amdgcn_fdot2)
  return __builtin_amdgcn_fdot2(a, b, c, false);
#else
  return fmaf((float)a.x, (float)b.x, fmaf((float)a.y, (float)b.y, c));
#endif
}

// butterfly-add a float across lanes via ds_swizzle (imm must be literal)
#define SWZF(v, imm) __uint_as_float((u32)__builtin_amdgcn_ds_swizzle((int)__float_as_uint(v), (imm)))

__device__ __forceinline__ bool is_fp32(const void* degsrc){
  // deg = exact ints 1..7: fp32 word0 low16 == 0; bf16 word0 low16 != 0
  return ((*(const u32*)degsrc) & 0xffffu) == 0u;
}

__device__ __forceinline__ bf16x8 cvt8(float4 a, float4 b){
  bf16x8 r;
  r[0]=(short)f2b(a.x); r[1]=(short)f2b(a.y); r[2]=(short)f2b(a.z); r[3]=(short)f2b(a.w);
  r[4]=(short)f2b(b.x); r[5]=(short)f2b(b.y); r[6]=(short)f2b(b.z); r[7]=(short)f2b(b.w);
  return r;
}

// ---------------------------------------------------------------------------
// k_convert: normalize small float params (+deg) into the arena.
// GW/VW -> f16 (consumed by k_agg dot2); everything else -> bf16.
// ---------------------------------------------------------------------------
__device__ __forceinline__ u16 cvt_one(const void* src, int j, bool f32){
  return f32 ? f2b(((const float*)src)[j]) : ((const u16*)src)[j];
}
__device__ __forceinline__ u16 cvt_one_h(const void* src, int j, bool f32){
  return f32 ? f2h(((const float*)src)[j]) : f2h(b2f(((const u16*)src)[j]));
}

__global__ void k_convert(const void* w0, const void* b0, const void* w1, const void* b1,
                          const void* emb, const void* gw, const void* vw,
                          const void* pw, const void* pb, const void* dp,
                          const void* degsrc, u16* __restrict__ pb16, int total)
{
  const int i = blockIdx.x * 256 + threadIdx.x;
  if (i >= total) return;
  const bool f32 = is_fp32(degsrc);
  u16 v;
  if      (i < OFF_B0 ) v = cvt_one(w0,  i,           f32);
  else if (i < OFF_W1 ) v = cvt_one(b0,  i - OFF_B0,  f32);
  else if (i < OFF_B1 ) v = cvt_one(w1,  i - OFF_W1,  f32);
  else if (i < OFF_EMB) v = cvt_one(b1,  i - OFF_B1,  f32);
  else if (i < OFF_GW ) v = cvt_one(emb, i - OFF_EMB, f32);
  else if (i < OFF_VW ) v = cvt_one_h(gw, i - OFF_GW, f32);   // f16
  else if (i < OFF_PW ) v = cvt_one_h(vw, i - OFF_VW, f32);   // f16
  else if (i < OFF_PB ) v = cvt_one(pw,  i - OFF_PW,  f32);
  else if (i < OFF_DP ) v = cvt_one(pb,  i - OFF_PB,  f32);
  else if (i < OFF_DEG) v = cvt_one(dp,  i - OFF_DP,  f32);
  else                  v = cvt_one(degsrc, i - OFF_DEG, f32);
  pb16[i] = v;
}

__device__ __forceinline__ float read_f(const void* src, int j, bool f32){
  return f32 ? ((const float*)src)[j] : b2f(((const u16*)src)[j]);
}

// gemb[a][c] = sum_i gw[c][i] * emb[a][(c/16)*16 + i]   (f32, 33x128)
__global__ void k_gemb(const void* gwsrc, const void* embsrc, const void* degsrc,
                       float* __restrict__ gemb)
{
  const int tid = blockIdx.x * 256 + threadIdx.x;
  if (tid >= 33 * 128) return;
  const bool f32 = is_fp32(degsrc);
  const int a = tid >> 7, c = tid & 127, g = c >> 4;
  float s = 0.f;
  #pragma unroll
  for (int i = 0; i < 16; ++i)
    s += read_f(gwsrc, c * 16 + i, f32) * read_f(embsrc, a * WIDTH + g * 16 + i, f32);
  gemb[tid] = s;
}

// ---------------------------------------------------------------------------
// counting-sort chain: zero -> hist -> scan1 -> scan2 -> scan3 -> scatter
// ---------------------------------------------------------------------------
__global__ void k_zero(int* __restrict__ cnt, int n){
  const int i = blockIdx.x * 256 + threadIdx.x;
  if (i < n) cnt[i] = 0;
}

__global__ void k_hist(const int* __restrict__ eidx, int* __restrict__ cnt, int E){
  const int e = blockIdx.x * 256 + threadIdx.x;
  if (e < E) atomicAdd(&cnt[eidx[E + e]], 1);
}

// block sums over 1024-elem chunks
__global__ void k_scan1(const int* __restrict__ cnt, int* __restrict__ bsum, int n){
  const int t = threadIdx.x, b = blockIdx.x;
  const int i0 = b * 1024 + t * 4;
  int s = 0;
  #pragma unroll
  for (int j = 0; j < 4; ++j) { int i = i0 + j; if (i < n) s += cnt[i]; }
  __shared__ int sb[256];
  sb[t] = s; __syncthreads();
  for (int d = 128; d > 0; d >>= 1) { if (t < d) sb[t] += sb[t + d]; __syncthreads(); }
  if (t == 0) bsum[b] = sb[0];
}

// single-block exclusive scan of bsum[0..nblk), nblk <= 1024
__global__ void k_scan2(int* __restrict__ bsum, int nblk){
  const int t = threadIdx.x;
  int v[4];
  const int i0 = t * 4;
  #pragma unroll
  for (int j = 0; j < 4; ++j) { int i = i0 + j; v[j] = (i < nblk) ? bsum[i] : 0; }
  int tsum = v[0] + v[1] + v[2] + v[3];
  __shared__ int sb[256];
  sb[t] = tsum; __syncthreads();
  for (int d = 1; d < 256; d <<= 1) {
    int x = (t >= d) ? sb[t - d] : 0;
    __syncthreads();
    sb[t] += x;
    __syncthreads();
  }
  int run = sb[t] - tsum;            // exclusive prefix of this thread
  #pragma unroll
  for (int j = 0; j < 4; ++j) { int nv = run; run += v[j]; v[j] = nv; }
  #pragma unroll
  for (int j = 0; j < 4; ++j) { int i = i0 + j; if (i < nblk) bsum[i] = v[j]; }
}

// full exclusive scan: off[i] = bsum[b] + local exclusive prefix
__global__ void k_scan3(const int* __restrict__ cnt, const int* __restrict__ bsum,
                        int* __restrict__ off, int n){
  const int t = threadIdx.x, b = blockIdx.x;
  const int i0 = b * 1024 + t * 4;
  int c[4];
  #pragma unroll
  for (int j = 0; j < 4; ++j) { int i = i0 + j; c[j] = (i < n) ? cnt[i] : 0; }
  int tsum = c[0] + c[1] + c[2] + c[3];
  __shared__ int sb[256];
  sb[t] = tsum; __syncthreads();
  for (int d = 1; d < 256; d <<= 1) {
    int x = (t >= d) ? sb[t - d] : 0;
    __syncthreads();
    sb[t] += x;
    __syncthreads();
  }
  int run = bsum[b] + sb[t] - tsum;
  #pragma unroll
  for (int j = 0; j < 4; ++j) {
    int i = i0 + j;
    if (i < n) off[i] = run;
    run += c[j];
  }
}

// scatter edges into dst-sorted order; off[dst] becomes END pointer after this
__global__ void k_scatter(const int* __restrict__ eidx, const int* __restrict__ eattr,
                          int* __restrict__ off, u32* __restrict__ ssrc,
                          u32* __restrict__ sattr, int E){
  const int e = blockIdx.x * 256 + threadIdx.x;
  if (e >= E) return;
  const int dst = eidx[E + e];
  const int pos = atomicAdd(&off[dst], 1);
  ssrc[pos] = (u32)eidx[e];
  const u32 a0 = (u32)eattr[e*3+0], a1 = (u32)eattr[e*3+1], a2 = (u32)eattr[e*3+2];
  sattr[pos] = a0 | (a1 << 6) | (a2 << 12);
}

// ---------------------------------------------------------------------------
// k_pre: h0 = x@w0^T + b0, h1 = x@w1^T + b1 via MFMA 16x16x32 bf16, f16 out.
// ---------------------------------------------------------------------------
__global__ __launch_bounds__(256, 2) void k_pre(
    const void* __restrict__ x, const u16* __restrict__ pb16,
    u16* __restrict__ h0, u16* __restrict__ h1, const void* __restrict__ degsrc)
{
  const int t = threadIdx.x;
  const int lane = t & 63, lid = lane & 15, quad = lane >> 4;
  const int w = t >> 6, mat = w >> 1, c0 = (w & 1) * 64;
  const int node0 = blockIdx.x * 64;

  const u16* wm = pb16 + (mat ? OFF_W1 : OFF_W0);
  const u16* bs = pb16 + (mat ? OFF_B1 : OFF_B0);
  u16* hout = mat ? h1 : h0;
  const bool f32 = is_fp32(degsrc);

  f32x4 acc[4][4];
  #pragma unroll
  for (int nt = 0; nt < 4; ++nt) {
    const float bias = b2f(bs[c0 + nt * 16 + lid]);
    #pragma unroll
    for (int mt = 0; mt < 4; ++mt)
      #pragma unroll
      for (int r = 0; r < 4; ++r) acc[mt][nt][r] = bias;
  }

  #pragma unroll
  for (int ks = 0; ks < 4; ++ks) {
    bf16x8 a[4], b[4];
    #pragma unroll
    for (int nt = 0; nt < 4; ++nt)
      b[nt] = *(const bf16x8*)(wm + (size_t)(c0 + nt * 16 + lid) * WIDTH + ks * 32 + quad * 8);
    if (f32) {
      #pragma unroll
      for (int mt = 0; mt < 4; ++mt) {
        const float4* xr = (const float4*)((const float*)x +
            (size_t)(node0 + mt * 16 + lid) * WIDTH + ks * 32 + quad * 8);
        a[mt] = cvt8(xr[0], xr[1]);
      }
    } else {
      #pragma unroll
      for (int mt = 0; mt < 4; ++mt)
        a[mt] = *(const bf16x8*)((const u16*)x +
            (size_t)(node0 + mt * 16 + lid) * WIDTH + ks * 32 + quad * 8);
    }
    #pragma unroll
    for (int mt = 0; mt < 4; ++mt)
      #pragma unroll
      for (int nt = 0; nt < 4; ++nt)
        acc[mt][nt] = __builtin_amdgcn_mfma_f32_16x16x32_bf16(a[mt], b[nt], acc[mt][nt], 0, 0, 0);
  }

  #pragma unroll
  for (int mt = 0; mt < 4; ++mt)
    #pragma unroll
    for (int nt = 0; nt < 4; ++nt)
      #pragma unroll
      for (int r = 0; r < 4; ++r)
        hout[(size_t)(node0 + mt * 16 + quad * 4 + r) * WIDTH + c0 + nt * 16 + lid] =
            f2h(acc[mt][nt][r]);
}

// ---------------------------------------------------------------------------
// k_agg: one wave per dst node. Lane q owns channels {2q, 2q+1}; 8-lane
// clusters = one 16-ch head. Per edge: gather h0[src] (packed f16 pair),
// pk_add h1, GroupNorm via dot2 + swizzle butterflies, grouped conv as
// broadcast-j ds_swizzle + v_dot2_f32_f16 with compile-time weight index,
// accumulate relu(g)*v, one plain float2 store to agg[dst].
// ---------------------------------------------------------------------------
__global__ __launch_bounds__(256, 4) void k_agg(
    const u16* __restrict__ h0, const u16* __restrict__ h1,
    const u32* __restrict__ ssrc, const u32* __restrict__ sattr,
    const int* __restrict__ off, const u16* __restrict__ pb16,
    const float* __restrict__ gemb, float* __restrict__ agg, const int N)
{
  const int dst = (blockIdx.x * 256 + threadIdx.x) >> 6;   // one wave per dst
  if (dst >= N) return;
  const int q = threadIdx.x & 63;
  const int c0 = 2 * q;           // my channels: c0, c0+1

  // conv rows c0, c0+1 as packed f16 pairs; index is compile-time in the loop
  u32 gw0[8], gw1[8], vw0[8], vw1[8];
  {
    const u32* g = (const u32*)(pb16 + OFF_GW + (size_t)c0 * 16);
    const u32* v = (const u32*)(pb16 + OFF_VW + (size_t)c0 * 16);
    #pragma unroll
    for (int i = 0; i < 8; ++i) {
      gw0[i] = g[i]; gw1[i] = g[8 + i];
      vw0[i] = v[i]; vw1[i] = v[8 + i];
    }
  }

  const f16x2 h1h  = u2h(*(const u32*)(h1 + (size_t)dst * WIDTH + c0));
  const f16x2 ones = u2h(0x3C003C00u);   // (1.0h, 1.0h)

  const int n0 = dst ? off[dst - 1] : 0;   // off[] holds end pointers post-scatter
  const int n1 = off[dst];

  float acc0 = 0.f, acc1 = 0.f;

  // prefetch edge n0
  u32 apw = 0, hp = 0;
  if (n0 < n1) {
    const u32 s0 = ssrc[n0];
    apw = sattr[n0];
    hp  = *(const u32*)(h0 + (size_t)s0 * WIDTH + c0);
  }

  for (int i = n0; i < n1; ++i) {
    const u32 apw_c = apw, hp_c = hp;
    if (i + 1 < n1) {                       // wave-uniform branch
      const u32 s2 = ssrc[i + 1];
      apw = sattr[i + 1];
      hp  = *(const u32*)(h0 + (size_t)s2 * WIDTH + c0);
    }

    // x = h0[src] + h1[dst], packed f16
    const f16x2 xh = u2h(hp_c) + h1h;       // v_pk_add_f16

    // GroupNorm stats over the 16-ch head (8-lane cluster)
    float s  = dot2h(xh, ones, 0.f);
    float ss = dot2h(xh, xh,   0.f);
    s  += SWZF(s,  0x041F); s  += SWZF(s,  0x081F); s  += SWZF(s,  0x101F);
    ss += SWZF(ss, 0x041F); ss += SWZF(ss, 0x081F); ss += SWZF(ss, 0x101F);
    const float mean = s * 0.0625f;
    const float var  = fmaf(ss, 0.0625f, -mean * mean);
    const float rs   = __builtin_amdgcn_rsqf(var + 1e-5f);
    const float mrs  = mean * rs;
    const float x0 = (float)xh.x, x1 = (float)xh.y;
    const f16x2 xn = __builtin_amdgcn_cvt_pkrtz(fmaf(x0, rs, -mrs), fmaf(x1, rs, -mrs));
    const u32 xnu = h2u(xn);

    // EmbeddingBag-mean pre-projected through gate weights (gemb), f32
    const int a0 = apw_c & 63, a1 = (apw_c >> 6) & 63, a2 = (apw_c >> 12) & 63;
    const float2 g0 = *(const float2*)(gemb + (size_t)a0 * WIDTH + c0);
    const float2 g1 = *(const float2*)(gemb + (size_t)a1 * WIDTH + c0);
    const float2 g2 = *(const float2*)(gemb + (size_t)a2 * WIDTH + c0);
    const int cb = (a0 != 0) + (a1 != 0) + (a2 != 0);
    const float inv = __builtin_amdgcn_rcpf((float)(cb | (cb == 0)));

    float ga0 = (g0.x + g1.x + g2.x) * inv;
    float ga1 = (g0.y + g1.y + g2.y) * inv;
    float va0 = 0.f, va1 = 0.f;

    // grouped conv: broadcast cluster-lane J's xn pair, weight index literal
#define CSTEP(J) {                                                             \
    const f16x2 xj = u2h((u32)__builtin_amdgcn_ds_swizzle(                     \
        (int)xnu, 0x18 | ((J) << 5)));                                         \
    ga0 = dot2h(xj, u2h(gw0[J]), ga0);                                         \
    ga1 = dot2h(xj, u2h(gw1[J]), ga1);                                         \
    va0 = dot2h(xj, u2h(vw0[J]), va0);                                         \
    va1 = dot2h(xj, u2h(vw1[J]), va1); }
    CSTEP(0) CSTEP(1) CSTEP(2) CSTEP(3) CSTEP(4) CSTEP(5) CSTEP(6) CSTEP(7)
#undef CSTEP

    acc0 = fmaf(fmaxf(ga0, 0.f), va0, acc0);
    acc1 = fmaf(fmaxf(ga1, 0.f), va1, acc1);
  }
  *(float2*)(agg + (size_t)dst * WIDTH + c0) = make_float2(acc0, acc1);
}

// ---------------------------------------------------------------------------
// k_post: out = (agg @ pw^T + pb) * deg^dp via MFMA.
// ---------------------------------------------------------------------------
__global__ __launch_bounds__(256, 2) void k_post(
    const float* __restrict__ agg, const u16* __restrict__ pb16,
    void* __restrict__ out, const void* __restrict__ degsrc)
{
  const int t = threadIdx.x;
  const int lane = t & 63, lid = lane & 15, quad = lane >> 4;
  const int w = t >> 6, c0 = (w & 1) * 64, mh = (w >> 1) * 32;
  const int node0 = blockIdx.x * 64;
  const bool f32o = is_fp32(degsrc);

  f32x4 acc[2][4];
  float dpc[4];
  #pragma unroll
  for (int nt = 0; nt < 4; ++nt) {
    const float bias = b2f(pb16[OFF_PB + c0 + nt * 16 + lid]);
    dpc[nt] = b2f(pb16[OFF_DP + c0 + nt * 16 + lid]);
    #pragma unroll
    for (int mt = 0; mt < 2; ++mt)
      #pragma unroll
      for (int r = 0; r < 4; ++r) acc[mt][nt][r] = bias;
  }

  #pragma unroll
  for (int ks = 0; ks < 4; ++ks) {
    bf16x8 a[2], b[4];
    #pragma unroll
    for (int nt = 0; nt < 4; ++nt)
      b[nt] = *(const bf16x8*)(pb16 + OFF_PW + (size_t)(c0 + nt * 16 + lid) * WIDTH + ks * 32 + quad * 8);
    #pragma unroll
    for (int mt = 0; mt < 2; ++mt) {
      const float4* ar = (const float4*)(agg +
          (size_t)(node0 + mh + mt * 16 + lid) * WIDTH + ks * 32 + quad * 8);
      a[mt] = cvt8(ar[0], ar[1]);
    }
    #pragma unroll
    for (int mt = 0; mt < 2; ++mt)
      #pragma unroll
      for (int nt = 0; nt < 4; ++nt)
        acc[mt][nt] = __builtin_amdgcn_mfma_f32_16x16x32_bf16(a[mt], b[nt], acc[mt][nt], 0, 0, 0);
  }

  float logd[2][4];
  #pragma unroll
  for (int mt = 0; mt < 2; ++mt)
    #pragma unroll
    for (int r = 0; r < 4; ++r)
      logd[mt][r] = __logf(b2f(pb16[OFF_DEG + node0 + mh + mt * 16 + quad * 4 + r]));

  #pragma unroll
  for (int mt = 0; mt < 2; ++mt)
    #pragma unroll
    for (int nt = 0; nt < 4; ++nt)
      #pragma unroll
      for (int r = 0; r < 4; ++r) {
        const int node = node0 + mh + mt * 16 + quad * 4 + r;
        const float v = acc[mt][nt][r] * __expf(dpc[nt] * logd[mt][r]);
        if (f32o) ((float*)out)[(size_t)node * WIDTH + c0 + nt * 16 + lid] = v;
        else      ((u16*)out)[(size_t)node * WIDTH + c0 + nt * 16 + lid] = f2b(v);
      }
}

extern "C" void kernel_launch(void* const* d_in, const int* in_sizes, int n_in,
                              void* d_out, int out_size, void* d_ws, size_t ws_size,
                              hipStream_t stream)
{
  (void)n_in; (void)out_size; (void)ws_size;
  const void* x     = d_in[0];
  const void* deg   = d_in[1];
  const int*  eidx  = (const int*)d_in[2];
  const int*  eattr = (const int*)d_in[3];

  const int N = in_sizes[1];            // 200000
  const int E = in_sizes[2] / 2;        // 1000000

  float* agg  = (float*)d_ws;
  u16*   h1   = (u16*)(agg + (size_t)N * WIDTH);
  u16*   pb16 = h1 + (size_t)N * WIDTH;
  float* gemb = (float*)(pb16 + ARENA_PAD);
  int*   cnt  = (int*)(gemb + 33 * WIDTH);
  int*   off  = cnt + N;
  int*   bsum = off + N;
  u32*   ssrc = (u32*)(bsum + 1024);
  u32*   sattr= ssrc + E;
  u16*   h0   = (u16*)d_out;            // f16 scratch; overwritten by k_post

  const int total = OFF_DEG + N;
  k_convert<<<(total + 255) / 256, 256, 0, stream>>>(
      d_in[4], d_in[5], d_in[6], d_in[7], d_in[8], d_in[9], d_in[10],
      d_in[11], d_in[12], d_in[13], deg, pb16, total);
  k_gemb<<<(33 * 128 + 255) / 256, 256, 0, stream>>>(d_in[9], d_in[8], deg, gemb);

  const int nb = N / 64;                // 3125
  k_pre<<<nb, 256, 0, stream>>>(x, pb16, h0, h1, deg);

  const int nblk = (N + 1023) / 1024;   // 196
  k_zero   <<<(N + 255) / 256, 256, 0, stream>>>(cnt, N);
  k_hist   <<<(E + 255) / 256, 256, 0, stream>>>(eidx, cnt, E);
  k_scan1  <<<nblk, 256, 0, stream>>>(cnt, bsum, N);
  k_scan2  <<<1, 256, 0, stream>>>(bsum, nblk);
  k_scan3  <<<nblk, 256, 0, stream>>>(cnt, bsum, off, N);
  k_scatter<<<(E + 255) / 256, 256, 0, stream>>>(eidx, eattr, off, ssrc, sattr, E);

  k_agg<<<(N * 64 + 255) / 256, 256, 0, stream>>>(
      h0, h1, ssrc, sattr, off, pb16, gemb, agg, N);

  k_post<<<nb, 256, 0, stream>>>(agg, pb16, d_out, deg);
}

// Round 2
// 609.865 us; speedup vs baseline: 1.5298x; 1.1290x over previous
//
#include <hip/hip_runtime.h>
#include <hip/hip_bf16.h>
#include <hip/hip_fp16.h>

// MetaGIN round 6:
//  - k_agg: linearized GroupNorm (conv on raw x; affine fix-up with rowsum(W))
//    so the conv dot2 stream overlaps the norm reduce; DPP butterfly reduce
//    (quad_perm/row_half_mirror) replaces ds_swizzle chain; 4 dst nodes per
//    wave amortize weight prologue; gemb in f16; agg stored f16.
//  - k_scatter: single 8B uint2 store per edge (src,attr packed).
//  - k_post: f16 MFMA directly on f16 agg + f16 PW.
//  - fused launches: k_init {zero cnt, convert params, gemb(f16), gsums},
//    k_pre_hist {node GEMMs + degree histogram}.
//
// ws layout: agg N*128 f32-slot (used as f16) | h1 N*128 f16 | pb16 arena |
//            gembh 33*128 f16 | gsums 256 f32 | cnt N i32 | off N i32 |
//            bsum 1024 i32 | sedge E uint2
// h0 (N*128 f16) lives in d_out (fully overwritten by k_post at the end).

typedef unsigned short u16;
typedef unsigned int   u32;

#define WIDTH 128

// params arena element offsets (bf16 except GW/VW/PW which are f16)
#define OFF_W0   0        // 16384
#define OFF_B0   16384    // 128
#define OFF_W1   16512    // 16384
#define OFF_B1   32896    // 128
#define OFF_EMB  33024    // 33*128 = 4224
#define OFF_GW   37248    // 128*16 = 2048 (f16)
#define OFF_VW   39296    // 2048 (f16)
#define OFF_PW   41344    // 16384 (f16)
#define OFF_PB   57728    // 128
#define OFF_DP   57856    // 128
#define OFF_DEG  57984    // N
#define ARENA_PAD 258048  // u16 elems (>= OFF_DEG+N, even)

typedef __attribute__((ext_vector_type(8))) short bf16x8;
typedef __attribute__((ext_vector_type(8))) _Float16 f16x8;
typedef __attribute__((ext_vector_type(4))) float f32x4;
typedef __attribute__((ext_vector_type(2))) __fp16 f16x2;

__device__ __forceinline__ float b2f(u16 u){ return __uint_as_float(((u32)u) << 16); }
__device__ __forceinline__ u16   f2b(float f){
  u32 u = __float_as_uint(f);
  u += 0x7fffu + ((u >> 16) & 1u);   // RNE
  return (u16)(u >> 16);
}
__device__ __forceinline__ u16   f2h(float f){ return __half_as_ushort(__float2half(f)); }

__device__ __forceinline__ f16x2 u2h(u32 u){ union { u32 a; f16x2 b; } c; c.a = u; return c.b; }
__device__ __forceinline__ u32   h2u(f16x2 h){ union { f16x2 b; u32 a; } c; c.b = h; return c.a; }

__device__ __forceinline__ float dot2h(f16x2 a, f16x2 b, float c){
#if __has_builtin(__builtin_amdgcn_fdot2)
  return __builtin_amdgcn_fdot2(a, b, c, false);
#else
  return fmaf((float)a.x, (float)b.x, fmaf((float)a.y, (float)b.y, c));
#endif
}

// s += dpp_xlane(s); ctrl literal. 0xB1=quad_perm xor1, 0x4E=quad_perm xor2,
// 0x141=row_half_mirror (xor7 within 8) -> full 8-lane butterfly in VALU.
#define DPPADD(s, ctrl) {                                                  \
  const float _t = __uint_as_float((u32)__builtin_amdgcn_update_dpp(       \
      0, (int)__float_as_uint(s), (ctrl), 0xF, 0xF, true));                \
  (s) += _t; }

__device__ __forceinline__ bool is_fp32(const void* degsrc){
  // deg = exact ints 1..7: fp32 word0 low16 == 0; bf16 word0 low16 != 0
  return ((*(const u32*)degsrc) & 0xffffu) == 0u;
}

__device__ __forceinline__ bf16x8 cvt8(float4 a, float4 b){
  bf16x8 r;
  r[0]=(short)f2b(a.x); r[1]=(short)f2b(a.y); r[2]=(short)f2b(a.z); r[3]=(short)f2b(a.w);
  r[4]=(short)f2b(b.x); r[5]=(short)f2b(b.y); r[6]=(short)f2b(b.z); r[7]=(short)f2b(b.w);
  return r;
}

__device__ __forceinline__ u16 cvt_one(const void* src, int j, bool f32){
  return f32 ? f2b(((const float*)src)[j]) : ((const u16*)src)[j];
}
__device__ __forceinline__ u16 cvt_one_h(const void* src, int j, bool f32){
  return f32 ? f2h(((const float*)src)[j]) : f2h(b2f(((const u16*)src)[j]));
}
__device__ __forceinline__ float read_f(const void* src, int j, bool f32){
  return f32 ? ((const float*)src)[j] : b2f(((const u16*)src)[j]);
}

// ---------------------------------------------------------------------------
// k_init: fused {zero cnt | convert params -> arena | gemb (f16) | gsums}.
// gemb[a][c] = sum_i gw[c][i]*emb[a][(c/16)*16+i]; gsums[c]=rowsum gw,
// gsums[128+c]=rowsum vw (f32, from original precision sources).
// ---------------------------------------------------------------------------
__global__ void k_init(const void* w0, const void* b0, const void* w1, const void* b1,
                       const void* emb, const void* gw, const void* vw,
                       const void* pw, const void* pb, const void* dp,
                       const void* degsrc, u16* __restrict__ pb16,
                       u16* __restrict__ gembh, float* __restrict__ gsums,
                       int* __restrict__ cnt, int N, int total)
{
  const bool f32 = is_fp32(degsrc);
  const int nbz = (N + 255) >> 8;
  const int nbc = (total + 255) >> 8;
  int b = blockIdx.x;
  const int t = threadIdx.x;

  if (b < nbz) {                       // zero cnt
    const int i = b * 256 + t;
    if (i < N) cnt[i] = 0;
    return;
  }
  b -= nbz;
  if (b < nbc) {                       // convert params
    const int i = b * 256 + t;
    if (i >= total) return;
    u16 v;
    if      (i < OFF_B0 ) v = cvt_one(w0,  i,           f32);
    else if (i < OFF_W1 ) v = cvt_one(b0,  i - OFF_B0,  f32);
    else if (i < OFF_B1 ) v = cvt_one(w1,  i - OFF_W1,  f32);
    else if (i < OFF_EMB) v = cvt_one(b1,  i - OFF_B1,  f32);
    else if (i < OFF_GW ) v = cvt_one(emb, i - OFF_EMB, f32);
    else if (i < OFF_VW ) v = cvt_one_h(gw, i - OFF_GW, f32);   // f16
    else if (i < OFF_PW ) v = cvt_one_h(vw, i - OFF_VW, f32);   // f16
    else if (i < OFF_PB ) v = cvt_one_h(pw, i - OFF_PW, f32);   // f16
    else if (i < OFF_DP ) v = cvt_one(pb,  i - OFF_PB,  f32);
    else if (i < OFF_DEG) v = cvt_one(dp,  i - OFF_DP,  f32);
    else                  v = cvt_one(degsrc, i - OFF_DEG, f32);
    pb16[i] = v;
    return;
  }
  b -= nbc;
  if (b < 17) {                        // gemb (f16 out)
    const int tid = b * 256 + t;
    if (tid >= 33 * 128) return;
    const int a = tid >> 7, c = tid & 127, g = c >> 4;
    float s = 0.f;
    #pragma unroll
    for (int i = 0; i < 16; ++i)
      s += read_f(gw, c * 16 + i, f32) * read_f(emb, a * WIDTH + g * 16 + i, f32);
    gembh[tid] = f2h(s);
    return;
  }
  // gsums block: t in [0,256): [0,128)=rowsum(gw), [128,256)=rowsum(vw)
  if (t < 256) {
    const int c = t & 127;
    const void* src = (t >> 7) ? vw : gw;
    float s = 0.f;
    #pragma unroll
    for (int i = 0; i < 16; ++i) s += read_f(src, c * 16 + i, f32);
    gsums[t] = s;
  }
}

// ---------------------------------------------------------------------------
// k_pre_hist: blocks [0,npre) do node GEMMs h0/h1 (MFMA bf16, f16 out);
// blocks [npre, ...) do the degree histogram. Independent work, one launch.
// ---------------------------------------------------------------------------
__global__ __launch_bounds__(256, 2) void k_pre_hist(
    const void* __restrict__ x, const u16* __restrict__ pb16,
    u16* __restrict__ h0, u16* __restrict__ h1, const void* __restrict__ degsrc,
    const int* __restrict__ eidx, int* __restrict__ cnt, int E, int npre)
{
  if ((int)blockIdx.x >= npre) {
    const int e = ((int)blockIdx.x - npre) * 256 + threadIdx.x;
    if (e < E) atomicAdd(&cnt[eidx[E + e]], 1);
    return;
  }

  const int t = threadIdx.x;
  const int lane = t & 63, lid = lane & 15, quad = lane >> 4;
  const int w = t >> 6, mat = w >> 1, c0 = (w & 1) * 64;
  const int node0 = blockIdx.x * 64;

  const u16* wm = pb16 + (mat ? OFF_W1 : OFF_W0);
  const u16* bs = pb16 + (mat ? OFF_B1 : OFF_B0);
  u16* hout = mat ? h1 : h0;
  const bool f32 = is_fp32(degsrc);

  f32x4 acc[4][4];
  #pragma unroll
  for (int nt = 0; nt < 4; ++nt) {
    const float bias = b2f(bs[c0 + nt * 16 + lid]);
    #pragma unroll
    for (int mt = 0; mt < 4; ++mt)
      #pragma unroll
      for (int r = 0; r < 4; ++r) acc[mt][nt][r] = bias;
  }

  #pragma unroll
  for (int ks = 0; ks < 4; ++ks) {
    bf16x8 a[4], b[4];
    #pragma unroll
    for (int nt = 0; nt < 4; ++nt)
      b[nt] = *(const bf16x8*)(wm + (size_t)(c0 + nt * 16 + lid) * WIDTH + ks * 32 + quad * 8);
    if (f32) {
      #pragma unroll
      for (int mt = 0; mt < 4; ++mt) {
        const float4* xr = (const float4*)((const float*)x +
            (size_t)(node0 + mt * 16 + lid) * WIDTH + ks * 32 + quad * 8);
        a[mt] = cvt8(xr[0], xr[1]);
      }
    } else {
      #pragma unroll
      for (int mt = 0; mt < 4; ++mt)
        a[mt] = *(const bf16x8*)((const u16*)x +
            (size_t)(node0 + mt * 16 + lid) * WIDTH + ks * 32 + quad * 8);
    }
    #pragma unroll
    for (int mt = 0; mt < 4; ++mt)
      #pragma unroll
      for (int nt = 0; nt < 4; ++nt)
        acc[mt][nt] = __builtin_amdgcn_mfma_f32_16x16x32_bf16(a[mt], b[nt], acc[mt][nt], 0, 0, 0);
  }

  #pragma unroll
  for (int mt = 0; mt < 4; ++mt)
    #pragma unroll
    for (int nt = 0; nt < 4; ++nt)
      #pragma unroll
      for (int r = 0; r < 4; ++r)
        hout[(size_t)(node0 + mt * 16 + quad * 4 + r) * WIDTH + c0 + nt * 16 + lid] =
            f2h(acc[mt][nt][r]);
}

// ---------------------------------------------------------------------------
// counting-sort scan chain
// ---------------------------------------------------------------------------
__global__ void k_scan1(const int* __restrict__ cnt, int* __restrict__ bsum, int n){
  const int t = threadIdx.x, b = blockIdx.x;
  const int i0 = b * 1024 + t * 4;
  int s = 0;
  #pragma unroll
  for (int j = 0; j < 4; ++j) { int i = i0 + j; if (i < n) s += cnt[i]; }
  __shared__ int sb[256];
  sb[t] = s; __syncthreads();
  for (int d = 128; d > 0; d >>= 1) { if (t < d) sb[t] += sb[t + d]; __syncthreads(); }
  if (t == 0) bsum[b] = sb[0];
}

__global__ void k_scan2(int* __restrict__ bsum, int nblk){
  const int t = threadIdx.x;
  int v[4];
  const int i0 = t * 4;
  #pragma unroll
  for (int j = 0; j < 4; ++j) { int i = i0 + j; v[j] = (i < nblk) ? bsum[i] : 0; }
  int tsum = v[0] + v[1] + v[2] + v[3];
  __shared__ int sb[256];
  sb[t] = tsum; __syncthreads();
  for (int d = 1; d < 256; d <<= 1) {
    int x = (t >= d) ? sb[t - d] : 0;
    __syncthreads();
    sb[t] += x;
    __syncthreads();
  }
  int run = sb[t] - tsum;
  #pragma unroll
  for (int j = 0; j < 4; ++j) { int nv = run; run += v[j]; v[j] = nv; }
  #pragma unroll
  for (int j = 0; j < 4; ++j) { int i = i0 + j; if (i < nblk) bsum[i] = v[j]; }
}

__global__ void k_scan3(const int* __restrict__ cnt, const int* __restrict__ bsum,
                        int* __restrict__ off, int n){
  const int t = threadIdx.x, b = blockIdx.x;
  const int i0 = b * 1024 + t * 4;
  int c[4];
  #pragma unroll
  for (int j = 0; j < 4; ++j) { int i = i0 + j; c[j] = (i < n) ? cnt[i] : 0; }
  int tsum = c[0] + c[1] + c[2] + c[3];
  __shared__ int sb[256];
  sb[t] = tsum; __syncthreads();
  for (int d = 1; d < 256; d <<= 1) {
    int x = (t >= d) ? sb[t - d] : 0;
    __syncthreads();
    sb[t] += x;
    __syncthreads();
  }
  int run = bsum[b] + sb[t] - tsum;
  #pragma unroll
  for (int j = 0; j < 4; ++j) {
    int i = i0 + j;
    if (i < n) off[i] = run;
    run += c[j];
  }
}

// scatter edges into dst-sorted order; one 8B store per edge.
// off[dst] becomes END pointer after this.
__global__ void k_scatter(const int* __restrict__ eidx, const int* __restrict__ eattr,
                          int* __restrict__ off, uint2* __restrict__ sedge, int E){
  const int e = blockIdx.x * 256 + threadIdx.x;
  if (e >= E) return;
  const int dst = eidx[E + e];
  const int pos = atomicAdd(&off[dst], 1);
  const u32 a0 = (u32)eattr[e*3+0], a1 = (u32)eattr[e*3+1], a2 = (u32)eattr[e*3+2];
  sedge[pos] = make_uint2((u32)eidx[e], a0 | (a1 << 6) | (a2 << 12));
}

// ---------------------------------------------------------------------------
// k_agg: one wave per 4 consecutive dst nodes. Lane q owns channels
// {2q,2q+1}; 8-lane clusters = one 16-ch head. Linearized GroupNorm:
//   Conv(xn) = rs*Conv(x) - mean*rs*rowsum(W)
// so the conv dot2 stream (raw x, broadcast via ds_swizzle) overlaps the
// DPP-butterfly mean/var reduce. agg stored f16 (u32/lane).
// ---------------------------------------------------------------------------
__global__ __launch_bounds__(256, 4) void k_agg(
    const u16* __restrict__ h0, const u16* __restrict__ h1,
    const uint2* __restrict__ sedge, const int* __restrict__ off,
    const u16* __restrict__ pb16, const u16* __restrict__ gembh,
    const float* __restrict__ gsums, u16* __restrict__ aggh, const int N)
{
  const int base = ((blockIdx.x * 256 + threadIdx.x) >> 6) * 4;
  if (base >= N) return;
  const int q = threadIdx.x & 63;
  const int c0 = 2 * q;           // my channels: c0, c0+1

  // conv rows c0, c0+1 as packed f16 pairs; index literal in unrolled loop
  u32 gw0[8], gw1[8], vw0[8], vw1[8];
  {
    const u32* g = (const u32*)(pb16 + OFF_GW + (size_t)c0 * 16);
    const u32* v = (const u32*)(pb16 + OFF_VW + (size_t)c0 * 16);
    #pragma unroll
    for (int i = 0; i < 8; ++i) {
      gw0[i] = g[i]; gw1[i] = g[8 + i];
      vw0[i] = v[i]; vw1[i] = v[8 + i];
    }
  }
  const float gs0 = gsums[c0],           gs1 = gsums[c0 + 1];
  const float nv0 = -gsums[128 + c0],    nv1 = -gsums[128 + c0 + 1];
  const f16x2 ones = u2h(0x3C003C00u);   // (1.0h, 1.0h)

  u32 h1w[4]; int nend[4];
  #pragma unroll
  for (int d = 0; d < 4; ++d) {
    const int dst = min(base + d, N - 1);
    h1w[d]  = *(const u32*)(h1 + (size_t)dst * WIDTH + c0);
    nend[d] = off[dst];
  }
  int ncur = base ? off[base - 1] : 0;
  const int nlast = nend[3];

  // prefetch pipeline state (runs across dst boundaries)
  u32 hp = 0, g0w = 0, g1w = 0, g2w = 0; float pinv = 1.f;
  if (ncur < nlast) {
    const uint2 ep = sedge[ncur];
    hp  = *(const u32*)(h0 + (size_t)ep.x * WIDTH + c0);
    const int a0 = ep.y & 63, a1 = (ep.y >> 6) & 63, a2 = (ep.y >> 12) & 63;
    g0w = *(const u32*)(gembh + (size_t)a0 * WIDTH + c0);
    g1w = *(const u32*)(gembh + (size_t)a1 * WIDTH + c0);
    g2w = *(const u32*)(gembh + (size_t)a2 * WIDTH + c0);
    const int cb = (a0 != 0) + (a1 != 0) + (a2 != 0);
    pinv = __builtin_amdgcn_rcpf((float)(cb | (cb == 0)));
  }

  #pragma unroll
  for (int d = 0; d < 4; ++d) {
    const f16x2 h1h = u2h(h1w[d]);
    const int n1 = nend[d];
    float acc0 = 0.f, acc1 = 0.f;

    for (int i = ncur; i < n1; ++i) {
      const u32 hp_c = hp, g0c = g0w, g1c = g1w, g2c = g2w;
      const float inv_c = pinv;
      if (i + 1 < nlast) {                    // wave-uniform
        const uint2 ep = sedge[i + 1];
        hp  = *(const u32*)(h0 + (size_t)ep.x * WIDTH + c0);
        const int a0 = ep.y & 63, a1 = (ep.y >> 6) & 63, a2 = (ep.y >> 12) & 63;
        g0w = *(const u32*)(gembh + (size_t)a0 * WIDTH + c0);
        g1w = *(const u32*)(gembh + (size_t)a1 * WIDTH + c0);
        g2w = *(const u32*)(gembh + (size_t)a2 * WIDTH + c0);
        const int cb = (a0 != 0) + (a1 != 0) + (a2 != 0);
        pinv = __builtin_amdgcn_rcpf((float)(cb | (cb == 0)));
      }

      // x = h0[src] + h1[dst], packed f16 (raw, un-normalized)
      const f16x2 xh = u2h(hp_c) + h1h;
      const u32 xu = h2u(xh);

      // stats reduce over 16-ch head via DPP butterfly (VALU-only)
      float s  = dot2h(xh, ones, 0.f);
      float ss = dot2h(xh, xh,   0.f);
      DPPADD(s, 0xB1);  DPPADD(ss, 0xB1);    // xor1 (quad_perm)
      DPPADD(s, 0x4E);  DPPADD(ss, 0x4E);    // xor2 (quad_perm)
      DPPADD(s, 0x141); DPPADD(ss, 0x141);   // xor7 (row_half_mirror)
      const float mean = s * 0.0625f;
      const float var  = fmaf(ss, 0.0625f, -mean * mean);
      const float rs   = __builtin_amdgcn_rsqf(var + 1e-5f);
      const float mrs  = mean * rs;

      // grouped conv on RAW x: broadcast cluster-lane J, literal weight index
      float rg0 = 0.f, rg1 = 0.f, rv0 = 0.f, rv1 = 0.f;
#define CSTEP(J) {                                                             \
      const f16x2 xj = u2h((u32)__builtin_amdgcn_ds_swizzle(                   \
          (int)xu, 0x18 | ((J) << 5)));                                        \
      rg0 = dot2h(xj, u2h(gw0[J]), rg0);                                       \
      rg1 = dot2h(xj, u2h(gw1[J]), rg1);                                       \
      rv0 = dot2h(xj, u2h(vw0[J]), rv0);                                       \
      rv1 = dot2h(xj, u2h(vw1[J]), rv1); }
      CSTEP(0) CSTEP(1) CSTEP(2) CSTEP(3) CSTEP(4) CSTEP(5) CSTEP(6) CSTEP(7)
#undef CSTEP

      // EmbeddingBag-mean pre-projected through gate weights (f16 gemb)
      const f16x2 gsum3 = u2h(g0c) + u2h(g1c) + u2h(g2c);  // v_pk_add_f16
      const float bg0 = (float)gsum3.x * inv_c;
      const float bg1 = (float)gsum3.y * inv_c;

      // affine fix-up: G.xn = rs*G.x - mean*rs*rowsum(G); + bag term
      const float ga0 = fmaf(rs, rg0, fmaf(-mrs, gs0, bg0));
      const float ga1 = fmaf(rs, rg1, fmaf(-mrs, gs1, bg1));
      const float va0 = fmaf(rs, rv0, mrs * nv0);
      const float va1 = fmaf(rs, rv1, mrs * nv1);
      acc0 = fmaf(fmaxf(ga0, 0.f), va0, acc0);
      acc1 = fmaf(fmaxf(ga1, 0.f), va1, acc1);
    }

    if (base + d < N)
      *(u32*)(aggh + (size_t)(base + d) * WIDTH + c0) =
          h2u(__builtin_amdgcn_cvt_pkrtz(acc0, acc1));
    ncur = n1;
  }
}

// ---------------------------------------------------------------------------
// k_post: out = (agg @ pw^T + pb) * deg^dp via f16 MFMA (agg & pw are f16).
// ---------------------------------------------------------------------------
__global__ __launch_bounds__(256, 2) void k_post(
    const u16* __restrict__ aggh, const u16* __restrict__ pb16,
    void* __restrict__ out, const void* __restrict__ degsrc)
{
  const int t = threadIdx.x;
  const int lane = t & 63, lid = lane & 15, quad = lane >> 4;
  const int w = t >> 6, c0 = (w & 1) * 64, mh = (w >> 1) * 32;
  const int node0 = blockIdx.x * 64;
  const bool f32o = is_fp32(degsrc);

  f32x4 acc[2][4];
  float dpc[4];
  #pragma unroll
  for (int nt = 0; nt < 4; ++nt) {
    const float bias = b2f(pb16[OFF_PB + c0 + nt * 16 + lid]);
    dpc[nt] = b2f(pb16[OFF_DP + c0 + nt * 16 + lid]);
    #pragma unroll
    for (int mt = 0; mt < 2; ++mt)
      #pragma unroll
      for (int r = 0; r < 4; ++r) acc[mt][nt][r] = bias;
  }

  #pragma unroll
  for (int ks = 0; ks < 4; ++ks) {
    f16x8 a[2], b[4];
    #pragma unroll
    for (int nt = 0; nt < 4; ++nt)
      b[nt] = *(const f16x8*)(pb16 + OFF_PW + (size_t)(c0 + nt * 16 + lid) * WIDTH + ks * 32 + quad * 8);
    #pragma unroll
    for (int mt = 0; mt < 2; ++mt)
      a[mt] = *(const f16x8*)(aggh +
          (size_t)(node0 + mh + mt * 16 + lid) * WIDTH + ks * 32 + quad * 8);
    #pragma unroll
    for (int mt = 0; mt < 2; ++mt)
      #pragma unroll
      for (int nt = 0; nt < 4; ++nt)
        acc[mt][nt] = __builtin_amdgcn_mfma_f32_16x16x32_f16(a[mt], b[nt], acc[mt][nt], 0, 0, 0);
  }

  float logd[2][4];
  #pragma unroll
  for (int mt = 0; mt < 2; ++mt)
    #pragma unroll
    for (int r = 0; r < 4; ++r)
      logd[mt][r] = __logf(b2f(pb16[OFF_DEG + node0 + mh + mt * 16 + quad * 4 + r]));

  #pragma unroll
  for (int mt = 0; mt < 2; ++mt)
    #pragma unroll
    for (int nt = 0; nt < 4; ++nt)
      #pragma unroll
      for (int r = 0; r < 4; ++r) {
        const int node = node0 + mh + mt * 16 + quad * 4 + r;
        const float v = acc[mt][nt][r] * __expf(dpc[nt] * logd[mt][r]);
        if (f32o) ((float*)out)[(size_t)node * WIDTH + c0 + nt * 16 + lid] = v;
        else      ((u16*)out)[(size_t)node * WIDTH + c0 + nt * 16 + lid] = f2b(v);
      }
}

extern "C" void kernel_launch(void* const* d_in, const int* in_sizes, int n_in,
                              void* d_out, int out_size, void* d_ws, size_t ws_size,
                              hipStream_t stream)
{
  (void)n_in; (void)out_size; (void)ws_size;
  const void* x     = d_in[0];
  const void* deg   = d_in[1];
  const int*  eidx  = (const int*)d_in[2];
  const int*  eattr = (const int*)d_in[3];

  const int N = in_sizes[1];            // 200000
  const int E = in_sizes[2] / 2;        // 1000000

  u16*   aggh = (u16*)d_ws;             // slot reserves N*128 f32; used as f16
  u16*   h1   = (u16*)((float*)d_ws + (size_t)N * WIDTH);
  u16*   pb16 = h1 + (size_t)N * WIDTH;
  u16*   gembh= pb16 + ARENA_PAD;
  float* gsums= (float*)(gembh + 33 * WIDTH);
  int*   cnt  = (int*)(gsums + 256);
  int*   off  = cnt + N;
  int*   bsum = off + N;
  uint2* sedge= (uint2*)(bsum + 1024);
  u16*   h0   = (u16*)d_out;            // f16 scratch; overwritten by k_post

  const int total = OFF_DEG + N;
  const int nbz = (N + 255) / 256;
  const int nbc = (total + 255) / 256;
  k_init<<<nbz + nbc + 18, 256, 0, stream>>>(
      d_in[4], d_in[5], d_in[6], d_in[7], d_in[8], d_in[9], d_in[10],
      d_in[11], d_in[12], d_in[13], deg, pb16, gembh, gsums, cnt, N, total);

  const int npre = N / 64;              // 3125
  const int nbh  = (E + 255) / 256;     // 3907
  k_pre_hist<<<npre + nbh, 256, 0, stream>>>(x, pb16, h0, h1, deg, eidx, cnt, E, npre);

  const int nblk = (N + 1023) / 1024;   // 196
  k_scan1  <<<nblk, 256, 0, stream>>>(cnt, bsum, N);
  k_scan2  <<<1, 256, 0, stream>>>(bsum, nblk);
  k_scan3  <<<nblk, 256, 0, stream>>>(cnt, bsum, off, N);
  k_scatter<<<nbh, 256, 0, stream>>>(eidx, eattr, off, sedge, E);

  k_agg<<<((size_t)N * 16 + 255) / 256, 256, 0, stream>>>(
      h0, h1, sedge, off, pb16, gembh, gsums, aggh, N);

  k_post<<<N / 64, 256, 0, stream>>>(aggh, pb16, d_out, deg);
}